// Round 9
// baseline (456.434 us; speedup 1.0000x reference)
//
#include <hip/hip_runtime.h>
#include <hip/hip_bf16.h>

// GNN: h = x@We^T + be; 2x { h = relu(segsum(h[col],row) @ W^T + b) };
// out = relu(mean(h,1) @ Wc1^T + bc1) @ Wc2^T + bc2   (scalar fp32)
//
// Restructure: relu((A h) W^T + b) == relu(A (h W^T) + b)  (A = sparse adj).
// R15: fine-grained read/MFMA interleave. R14 (conflicts=0, staging
// coalesced) still measured 5272 cyc/tile ~= MFMA 2211 + LDS-read 2313 +
// writes 512 SERIAL. Cause: per-wave order {16 reads; 16 MFMA; 8 reload
// reads; 16 MFMA} puts lgkmcnt(0) on mid-tile reads -> two read-bursts /
// two MFMA-bursts, lockstep across 8 waves, 1 block/CU (128KB LDS) = no
// cross-block fill. Fix: 8 clusters of 4 MFMAs; reload af[r]<-frag(4+r)
// IMMEDIATELY after cluster r issues (WAR dep pins the read's position,
// consumer is 12-16 MFMAs later); staging spread across clusters. Same
// register count (12 live frags was the R10 spill; this keeps 8).
// R14: GLOBAL fragment-major operands -- staging src base+(t&127)*16 (1KB
// contiguous/wave) AND lane-linear LDS reads (0 conflicts, HW-verified):
//   addr(row,k) = ((row>>4)*(K>>7) + (k>>7))*2048 + ((k>>4)&1)*1024
//               + ((((k>>5)&3)<<4) | (row&15))*16 + (k&15)
// Producers: cvt_all permuted; gemm1 epilogue permuted (permC=1);
// aggr_f8out permuted; g row-major (aggr gathers).
// R13 ERRATA: SQ_LDS_BANK_CONFLICT was 8/ds_read_b128 (real; 128B-stride
// rows). R12: XCD-slab aggr (2MB L2-resident). R11: aggr+mean fused.
// GEMM schedule: 1 barrier/K-tile; boundary vmcnt(0) covered by a full
// tile of MFMA; compiler-counted lgkmcnt does fine sync.
//   - 256x256 tile, 512 threads, 8 waves (2Mx4N), BK=128, double-buffered
//     LDS (128 KiB), MX-scaled fp8 mfma_scale_f32_16x16x128_f8f6f4.
//   - XCD swizzle: 4x8 sub-rectangle of tiles per XCD (12 MB panel set).

#define N_NODES 4096
#define IN_DIM_ 512
#define HID_ 4096
#define NEDGE 65536

typedef float f32x4 __attribute__((ext_vector_type(4)));
typedef float f32x2 __attribute__((ext_vector_type(2)));
typedef unsigned short u16x8 __attribute__((ext_vector_type(8)));
typedef int i32x8 __attribute__((ext_vector_type(8)));

#define ACT_SCALE 8.0f     // activations fp8 = 8 x true
#define W_SCALE 256.0f     // weights fp8 = 256 x true
#define G_SCALE 8.0f       // g fp8 = 8 x true
// gemm acc = 2048 x true; fp8-store multiplier = 8/2048
#define G_STORE_MUL (8.0f / 2048.0f)

__device__ __forceinline__ unsigned short f2bf(float f) {
  unsigned u = __float_as_uint(f);
  return (unsigned short)((u + 0x7fffu + ((u >> 16) & 1u)) >> 16);  // RNE
}
__device__ __forceinline__ float bf2f(unsigned short h) {
  return __uint_as_float((unsigned)h << 16);
}
__device__ __forceinline__ unsigned char f2fp8(float f) {
  int w = __builtin_amdgcn_cvt_pk_fp8_f32(f, f, 0, false);  // OCP e4m3
  return (unsigned char)(w & 0xff);
}
// decode 4 fp8 bytes of w into acc[0..3] (+=)
__device__ __forceinline__ void fp8x4_acc(int w, float* acc) {
  f32x2 lo = __builtin_amdgcn_cvt_pk_f32_fp8(w, false);
  f32x2 hi = __builtin_amdgcn_cvt_pk_f32_fp8(w, true);
  acc[0] += lo[0]; acc[1] += lo[1]; acc[2] += hi[0]; acc[3] += hi[1];
}

// ---- fused fp32 -> fp8 e4m3 into FRAGMENT-MAJOR layout (R14) ----
// One thread = one 16B output slot S: decode S -> (row, k0..k0+15), read
// 64B of fp32, pack 16 fp8, write 16B at out+S*16 (contiguous writes).
// slot ranges (16B slots): x 131072 | We +131072 | W1 +1048576 | W2 +1048576
#define SL_X  131072L
#define SL_WE 262144L
#define SL_W1 1310720L
#define SL_W2 2359296L
__global__ __launch_bounds__(256) void cvt_all(
    const float* __restrict__ x, const float* __restrict__ We,
    const float* __restrict__ W1, const float* __restrict__ W2,
    unsigned char* __restrict__ xf8, unsigned char* __restrict__ wef8,
    unsigned char* __restrict__ w1f8, unsigned char* __restrict__ w2f8) {
  long S = (long)blockIdx.x * 256 + threadIdx.x;
  const float* src; unsigned char* dst; float sc; long So; int K, ktb;
  if (S < SL_X)       { src = x;  dst = xf8;  sc = ACT_SCALE; So = S;         K = 512;  ktb = 2; }
  else if (S < SL_WE) { src = We; dst = wef8; sc = W_SCALE;   So = S - SL_X;  K = 512;  ktb = 2; }
  else if (S < SL_W1) { src = W1; dst = w1f8; sc = W_SCALE;   So = S - SL_WE; K = 4096; ktb = 5; }
  else                { src = W2; dst = w2f8; sc = W_SCALE;   So = S - SL_W1; K = 4096; ktb = 5; }
  const long region = So >> 7;
  const int rem = (int)(So & 127);
  const int h = (rem >> 6) & 1, q = (rem >> 4) & 3, m = rem & 15;
  const long R16 = region >> ktb;
  const int kt = (int)(region & ((1 << ktb) - 1));
  const long row = R16 * 16 + m;
  const int k0 = kt * 128 + q * 32 + h * 16;
  const float* p = src + row * K + k0;
  const float4 a = *(const float4*)(p);
  const float4 b = *(const float4*)(p + 4);
  const float4 c = *(const float4*)(p + 8);
  const float4 d = *(const float4*)(p + 12);
  int w0 = __builtin_amdgcn_cvt_pk_fp8_f32(a.x * sc, a.y * sc, 0, false);
  w0 = __builtin_amdgcn_cvt_pk_fp8_f32(a.z * sc, a.w * sc, w0, true);
  int w1 = __builtin_amdgcn_cvt_pk_fp8_f32(b.x * sc, b.y * sc, 0, false);
  w1 = __builtin_amdgcn_cvt_pk_fp8_f32(b.z * sc, b.w * sc, w1, true);
  int w2 = __builtin_amdgcn_cvt_pk_fp8_f32(c.x * sc, c.y * sc, 0, false);
  w2 = __builtin_amdgcn_cvt_pk_fp8_f32(c.z * sc, c.w * sc, w2, true);
  int w3 = __builtin_amdgcn_cvt_pk_fp8_f32(d.x * sc, d.y * sc, 0, false);
  w3 = __builtin_amdgcn_cvt_pk_fp8_f32(d.z * sc, d.w * sc, w3, true);
  *(int4*)(dst + So * 16) = make_int4(w0, w1, w2, w3);
}

// ---------------- CSR build ----------------
__global__ __launch_bounds__(256) void zero_i32(int* __restrict__ p, int n) {
  int i = blockIdx.x * 256 + threadIdx.x;
  if (i < n) p[i] = 0;
}

__global__ __launch_bounds__(256) void hist_rows(const int* __restrict__ row,
                                                 int* __restrict__ counts) {
  int e = blockIdx.x * 256 + threadIdx.x;
  if (e < NEDGE) atomicAdd(&counts[row[e]], 1);
}

// exclusive scan of counts[4096] -> starts[4097]; single block of 1024 threads
__global__ __launch_bounds__(1024) void scan4096(const int* __restrict__ counts,
                                                 int* __restrict__ starts) {
  __shared__ int sa[1024], sb[1024];
  const int t = threadIdx.x;
  const int c0 = counts[t * 4], c1 = counts[t * 4 + 1],
            c2 = counts[t * 4 + 2], c3 = counts[t * 4 + 3];
  const int local = c0 + c1 + c2 + c3;
  sa[t] = local;
  __syncthreads();
  int* src = sa; int* dst = sb;
  for (int off = 1; off < 1024; off <<= 1) {
    int v = src[t];
    if (t >= off) v += src[t - off];
    dst[t] = v;
    __syncthreads();
    int* tmp = src; src = dst; dst = tmp;
  }
  const int excl = (t == 0) ? 0 : src[t - 1];
  starts[t * 4]     = excl;
  starts[t * 4 + 1] = excl + c0;
  starts[t * 4 + 2] = excl + c0 + c1;
  starts[t * 4 + 3] = excl + c0 + c1 + c2;
  if (t == 1023) starts[4096] = excl + local;
}

__global__ __launch_bounds__(256) void fill_adj(const int* __restrict__ row,
                                                const int* __restrict__ col,
                                                const int* __restrict__ starts,
                                                int* __restrict__ cursor,
                                                int* __restrict__ adj) {
  int e = blockIdx.x * 256 + threadIdx.x;
  if (e >= NEDGE) return;
  int r = row[e];
  int p = atomicAdd(&cursor[r], 1);
  adj[starts[r] + p] = col[e];
}

// ---- MX fp8 GEMM: C = fp8(mul*(A@B^T) [+ ACT_SCALE*bias]) ----
// A, B in fragment-major global layout; C row-major (permC=0) or
// fragment-major (permC=1). 256x256 tile, BK=128, 8 waves, 1 barrier/tile.
#define GLDS(gp, lp)                                                       \
  __builtin_amdgcn_global_load_lds(                                        \
      (const __attribute__((address_space(1))) void*)(gp),                 \
      (__attribute__((address_space(3))) void*)(lp), 16, 0, 0)

__global__ __launch_bounds__(512, 2) void gemm_mx(
    const unsigned char* __restrict__ A, const unsigned char* __restrict__ B,
    unsigned char* __restrict__ C, int N, int K,
    const float* __restrict__ bias, float mul, int permC) {
  __shared__ unsigned char lds[131072];   // [A dbuf 2x32K][B dbuf 2x32K]
  const int t = threadIdx.x;
  // XCD swizzle: XCD x owns a 4(bm) x 8(bn) sub-rectangle of the 16x16 tile
  // grid (bijective for nwg=256). 32 co-resident blocks/XCD share
  // 4 A-panels + 8 B-panels; per-K-step working set 384 KB << 4 MB L2.
  const int w = blockIdx.x;
  const int xcd = w & 7, j = w >> 3;
  const int bm = ((xcd & 3) * 4 + (j & 3)) * 256;
  const int bn = ((xcd >> 2) * 8 + (j >> 2)) * 256;
  const int wave = t >> 6, lane = t & 63;
  const int wm = (wave >> 2) * 128, wn = (wave & 3) * 64;
  const int m16 = lane & 15, quad = lane >> 4;

  f32x4 acc[8][4] = {};

  const int KT = K >> 7;
  // staging (fragment-major global): thread t, inst i, k-tile kt sources
  // base + ((bm>>4) + i*4 + (t>>7))*KT*2048 + kt*2048 + (t&127)*16 and
  // writes LDS byte i*8192 + t*16. Per wave: 1KB contiguous global reads.
  const unsigned char* Ag = A + ((size_t)(bm >> 4) + (t >> 7)) * KT * 2048 + (t & 127) * 16;
  const unsigned char* Bg = B + ((size_t)(bn >> 4) + (t >> 7)) * KT * 2048 + (t & 127) * 16;
  const size_t istep = (size_t)8192 * KT;      // +4 row-blocks per inst
  unsigned char* Als = lds;
  unsigned char* Bls = lds + 65536;
  const int sd = t * 16;
  const int lane16 = lane * 16;

#define STAGE_A(i, kb, dst) GLDS(Ag + (kb) + (size_t)(i) * istep, (dst) + (i) * 8192 + sd)
#define STAGE_B(i, kb, dst) GLDS(Bg + (kb) + (size_t)(i) * istep, (dst) + (i) * 8192 + sd)

  // lane-linear conflict-free fragment read (R13-verified: 0 conflicts)
#define LDFRAG(dst, base, fb)                                              \
  {                                                                        \
    const unsigned char* _p = (base) + (fb) * 2048 + lane16;               \
    const int4 _lo = *(const int4*)(_p);                                   \
    const int4 _hi = *(const int4*)(_p + 1024);                            \
    dst[0] = _lo.x; dst[1] = _lo.y; dst[2] = _lo.z; dst[3] = _lo.w;        \
    dst[4] = _hi.x; dst[5] = _hi.y; dst[6] = _hi.z; dst[7] = _hi.w;        \
  }

#define MFMA(r, c, afr, bfr)                                               \
  acc[r][c] = __builtin_amdgcn_mfma_scale_f32_16x16x128_f8f6f4(            \
      afr, bfr, acc[r][c], 0, 0, 0, 0x7f7f7f7f, 0, 0x7f7f7f7f)

  // 4-MFMA cluster for output row-frag r using A-regs a (all 4 B frags)
#define CLUSTER(r, a)                                                      \
  __builtin_amdgcn_s_setprio(1);                                           \
  MFMA(r, 0, a, bf01[0]); MFMA(r, 1, a, bf01[1]);                          \
  MFMA(r, 2, a, bf23[0]); MFMA(r, 3, a, bf23[1]);                          \
  __builtin_amdgcn_s_setprio(0);

  // A frag block base (16-row frags): wm/16; B frag base: wn/16
  const int afb = (wave >> 2) * 8;
  const int bfb = (wave & 3) * 4;

  // prologue: stage tile 0 into buf 0 (only exposed wait of the loop)
  STAGE_A(0, 0, Als); STAGE_A(1, 0, Als); STAGE_A(2, 0, Als); STAGE_A(3, 0, Als);
  STAGE_B(0, 0, Bls); STAGE_B(1, 0, Bls); STAGE_B(2, 0, Bls); STAGE_B(3, 0, Bls);
  asm volatile("s_waitcnt vmcnt(0)" ::: "memory");
  __builtin_amdgcn_s_barrier();

  i32x8 af[4], bf01[2], bf23[2];

  for (int tt = 0; tt < KT; ++tt) {
    unsigned char* Ab = Als + (tt & 1) * 32768;
    unsigned char* Bb = Bls + (tt & 1) * 32768;
    unsigned char* An = Als + ((tt + 1) & 1) * 32768;
    unsigned char* Bn = Bls + ((tt + 1) & 1) * 32768;
    const int kbn = (tt + 1) * 2048;
    const bool more = (tt + 1) < KT;

    // R15 interleave: cluster r's MFMAs issue as soon as their deps land;
    // af[r] is reloaded with frag 4+r IMMEDIATELY after cluster r (WAR dep
    // pins the read mid-stream; consumer cluster 4+r is 12-16 MFMAs away)
    // -> LDS service runs under MFMA issue for the whole tile.
    LDFRAG(af[0], Ab, afb + 0);
    LDFRAG(bf01[0], Bb, bfb + 0);
    LDFRAG(bf01[1], Bb, bfb + 1);
    LDFRAG(bf23[0], Bb, bfb + 2);
    LDFRAG(bf23[1], Bb, bfb + 3);
    LDFRAG(af[1], Ab, afb + 1);
    LDFRAG(af[2], Ab, afb + 2);
    LDFRAG(af[3], Ab, afb + 3);
    if (more) {
      STAGE_A(0, kbn, An); STAGE_A(1, kbn, An);
      STAGE_A(2, kbn, An); STAGE_A(3, kbn, An);
    }
    CLUSTER(0, af[0]);
    LDFRAG(af[0], Ab, afb + 4);
    if (more) { STAGE_B(0, kbn, Bn); STAGE_B(1, kbn, Bn); }
    CLUSTER(1, af[1]);
    LDFRAG(af[1], Ab, afb + 5);
    if (more) { STAGE_B(2, kbn, Bn); STAGE_B(3, kbn, Bn); }
    CLUSTER(2, af[2]);
    LDFRAG(af[2], Ab, afb + 6);
    CLUSTER(3, af[3]);
    LDFRAG(af[3], Ab, afb + 7);
    CLUSTER(4, af[0]);
    CLUSTER(5, af[1]);
    CLUSTER(6, af[2]);
    CLUSTER(7, af[3]);
    if (more) {
      // tile-boundary: t+1's staging (issued a near-full tile of MFMA ago)
      // has landed; all buf-cur reads were consumed above. ONLY barrier.
      asm volatile("s_waitcnt vmcnt(0)" ::: "memory");
      __builtin_amdgcn_sched_barrier(0);
      __builtin_amdgcn_s_barrier();
    }
  }

#undef CLUSTER
#undef MFMA
#undef LDFRAG
#undef STAGE_A
#undef STAGE_B

  // C/D layout (16x16 family, shape-determined): col=lane&15, row=quad*4+reg
  if (permC) {
    const int KTN = N >> 7;
#pragma unroll
    for (int r = 0; r < 8; ++r) {
#pragma unroll
      for (int c = 0; c < 4; ++c) {
        const int rb = ((bm + wm) >> 4) + r;          // row-block (rows>>4)
        const int colb = bn + wn + c * 16;            // 16-aligned col base
        const float bv = bias ? ACT_SCALE * bias[colb + m16] : 0.0f;
        const size_t base = ((size_t)rb * KTN + (colb >> 7)) * 2048
                          + (((colb >> 4) & 1) << 10)
                          + (((colb >> 5) & 3) << 8) + m16;
#pragma unroll
        for (int i = 0; i < 4; ++i) {
          C[base + (quad * 4 + i) * 16] = f2fp8(acc[r][c][i] * mul + bv);
        }
      }
    }
  } else {
#pragma unroll
    for (int r = 0; r < 8; ++r) {
#pragma unroll
      for (int c = 0; c < 4; ++c) {
        const int row0 = bm + wm + r * 16 + quad * 4;
        const int col = bn + wn + c * 16 + m16;
        const float bv = bias ? ACT_SCALE * bias[col] : 0.0f;
#pragma unroll
        for (int i = 0; i < 4; ++i) {
          C[(size_t)(row0 + i) * N + col] = f2fp8(acc[r][c][i] * mul + bv);
        }
      }
    }
  }
}
#undef GLDS

// ---- aggregation (fp8 g in, row-major): h = relu(sum g/G + b) -> fp8,
// written FRAGMENT-MAJOR (h1f8 is the next gemm's A operand).
// One wave per (node, 512-col slab); xcd = b&7 = slab -> 2 MB L2-resident.
__global__ __launch_bounds__(64) void aggr_f8out(
    const unsigned char* __restrict__ g, const int* __restrict__ starts,
    const int* __restrict__ adj, const float* __restrict__ bias,
    unsigned char* __restrict__ hout) {
  const int node = blockIdx.x >> 3;
  const int f0 = (blockIdx.x & 7) * 512 + threadIdx.x * 8;
  float acc[8] = {0, 0, 0, 0, 0, 0, 0, 0};
  const int s = starts[node], e = starts[node + 1];
  int j = s;
  for (; j + 4 <= e; j += 4) {
    const int c0 = adj[j], c1 = adj[j + 1], c2 = adj[j + 2], c3 = adj[j + 3];
    int2 v0 = *(const int2*)(g + (size_t)c0 * HID_ + f0);
    int2 v1 = *(const int2*)(g + (size_t)c1 * HID_ + f0);
    int2 v2 = *(const int2*)(g + (size_t)c2 * HID_ + f0);
    int2 v3 = *(const int2*)(g + (size_t)c3 * HID_ + f0);
    fp8x4_acc(v0.x, acc);     fp8x4_acc(v0.y, acc + 4);
    fp8x4_acc(v1.x, acc);     fp8x4_acc(v1.y, acc + 4);
    fp8x4_acc(v2.x, acc);     fp8x4_acc(v2.y, acc + 4);
    fp8x4_acc(v3.x, acc);     fp8x4_acc(v3.y, acc + 4);
  }
  for (; j < e; ++j) {
    int2 v = *(const int2*)(g + (size_t)adj[j] * HID_ + f0);
    fp8x4_acc(v.x, acc);      fp8x4_acc(v.y, acc + 4);
  }
  const float4 b0 = *(const float4*)(bias + f0);
  const float4 b1 = *(const float4*)(bias + f0 + 4);
  const float bb[8] = {b0.x, b0.y, b0.z, b0.w, b1.x, b1.y, b1.z, b1.w};
  float v[8];
#pragma unroll
  for (int i = 0; i < 8; ++i)
    v[i] = ACT_SCALE * fmaxf(acc[i] * (1.0f / G_SCALE) + bb[i], 0.0f);
  int w0 = __builtin_amdgcn_cvt_pk_fp8_f32(v[0], v[1], 0, false);
  w0 = __builtin_amdgcn_cvt_pk_fp8_f32(v[2], v[3], w0, true);
  int w1 = __builtin_amdgcn_cvt_pk_fp8_f32(v[4], v[5], 0, false);
  w1 = __builtin_amdgcn_cvt_pk_fp8_f32(v[6], v[7], w1, true);
  // fragment-major dest (K = HID, KT = 32); f0&15 in {0,8} -> 8B in-slot
  const size_t oaddr = ((size_t)(node >> 4) * 32 + (f0 >> 7)) * 2048
                     + (((f0 >> 4) & 1) << 10)
                     + (((f0 >> 5) & 3) << 8) + ((node & 15) << 4) + (f0 & 15);
  *(int2*)(hout + oaddr) = make_int2(w0, w1);
}

// ---- fused final aggregation + row mean: hm[node] += sum_f relu(.)/HID ----
// (h2 never materialized; g row-major; same XCD-slab structure)
__global__ __launch_bounds__(64) void aggr_mean(
    const unsigned char* __restrict__ g, const int* __restrict__ starts,
    const int* __restrict__ adj, const float* __restrict__ bias,
    float* __restrict__ hm) {
  const int node = blockIdx.x >> 3;
  const int f0 = (blockIdx.x & 7) * 512 + threadIdx.x * 8;
  float acc[8] = {0, 0, 0, 0, 0, 0, 0, 0};
  const int s = starts[node], e = starts[node + 1];
  int j = s;
  for (; j + 4 <= e; j += 4) {
    const int c0 = adj[j], c1 = adj[j + 1], c2 = adj[j + 2], c3 = adj[j + 3];
    int2 v0 = *(const int2*)(g + (size_t)c0 * HID_ + f0);
    int2 v1 = *(const int2*)(g + (size_t)c1 * HID_ + f0);
    int2 v2 = *(const int2*)(g + (size_t)c2 * HID_ + f0);
    int2 v3 = *(const int2*)(g + (size_t)c3 * HID_ + f0);
    fp8x4_acc(v0.x, acc);     fp8x4_acc(v0.y, acc + 4);
    fp8x4_acc(v1.x, acc);     fp8x4_acc(v1.y, acc + 4);
    fp8x4_acc(v2.x, acc);     fp8x4_acc(v2.y, acc + 4);
    fp8x4_acc(v3.x, acc);     fp8x4_acc(v3.y, acc + 4);
  }
  for (; j < e; ++j) {
    int2 v = *(const int2*)(g + (size_t)adj[j] * HID_ + f0);
    fp8x4_acc(v.x, acc);      fp8x4_acc(v.y, acc + 4);
  }
  const float4 b0 = *(const float4*)(bias + f0);
  const float4 b1 = *(const float4*)(bias + f0 + 4);
  const float bb[8] = {b0.x, b0.y, b0.z, b0.w, b1.x, b1.y, b1.z, b1.w};
  float local = 0.f;
#pragma unroll
  for (int i = 0; i < 8; ++i)
    local += fmaxf(acc[i] * (1.0f / G_SCALE) + bb[i], 0.0f);
  for (int off = 32; off > 0; off >>= 1) local += __shfl_down(local, off);
  if (threadIdx.x == 0)
    atomicAdd(&hm[node], local * (1.0f / (float)HID_));
}

// ---------------- z[j] = relu(Wc1[j,:].hm + bc1[j]), one wave per j ----------------
__global__ __launch_bounds__(256) void clf1(const float* __restrict__ Wc1,
                                            const float* __restrict__ bc1,
                                            const float* __restrict__ hm,
                                            float* __restrict__ z) {
  const int wave = threadIdx.x >> 6, lane = threadIdx.x & 63;
  const int j = blockIdx.x * 4 + wave;
  const float* w = Wc1 + (size_t)j * HID_;
  float s = 0.f;
  for (int i = lane; i < HID_; i += 64) s += w[i] * hm[i];
  for (int off = 32; off > 0; off >>= 1) s += __shfl_down(s, off);
  if (lane == 0) z[j] = fmaxf(s + bc1[j], 0.0f);
}

// ---------------- out = Wc2.z + bc2 ----------------
__global__ __launch_bounds__(256) void clf2(const float* __restrict__ Wc2,
                                            const float* __restrict__ bc2,
                                            const float* __restrict__ z,
                                            float* __restrict__ out) {
  const int t = threadIdx.x;
  float s = 0.f;
  for (int i = t; i < HID_ / 2; i += 256) s += z[i] * Wc2[i];
  for (int off = 32; off > 0; off >>= 1) s += __shfl_down(s, off);
  __shared__ float ws[4];
  if ((t & 63) == 0) ws[t >> 6] = s;
  __syncthreads();
  if (t == 0) out[0] = ws[0] + ws[1] + ws[2] + ws[3] + bc2[0];
}

extern "C" void kernel_launch(void* const* d_in, const int* in_sizes, int n_in,
                              void* d_out, int out_size, void* d_ws, size_t ws_size,
                              hipStream_t stream) {
  (void)in_sizes; (void)n_in; (void)out_size; (void)ws_size;
  const float* x       = (const float*)d_in[0];
  const int*   edge    = (const int*)d_in[1];
  const int*   row     = edge;
  const int*   col     = edge + NEDGE;
  const float* W_embed = (const float*)d_in[2];
  const float* b_embed = (const float*)d_in[3];
  const float* W1      = (const float*)d_in[4];
  const float* b1      = (const float*)d_in[5];
  const float* W2      = (const float*)d_in[6];
  const float* b2      = (const float*)d_in[7];
  const float* Wc1     = (const float*)d_in[8];
  const float* bc1     = (const float*)d_in[9];
  const float* Wc2     = (const float*)d_in[10];
  const float* bc2     = (const float*)d_in[11];
  float* out = (float*)d_out;

  char* ws = (char*)d_ws;
  size_t off = 0;
  auto alloc = [&](size_t bytes) {
    char* p = ws + off;
    off += (bytes + 255) & ~(size_t)255;
    return p;
  };
  unsigned char*  xf8  = (unsigned char*)alloc((size_t)N_NODES * IN_DIM_);
  unsigned char*  wef8 = (unsigned char*)alloc((size_t)HID_ * IN_DIM_);
  unsigned char*  w1f8 = (unsigned char*)alloc((size_t)HID_ * HID_);
  unsigned char*  w2f8 = (unsigned char*)alloc((size_t)HID_ * HID_);
  unsigned char*  h0f8 = (unsigned char*)alloc((size_t)N_NODES * HID_);
  unsigned char*  h1f8 = (unsigned char*)alloc((size_t)N_NODES * HID_);
  unsigned char*  g    = (unsigned char*)alloc((size_t)N_NODES * HID_);
  // counts | cursor | hm are allocated adjacently (each 16 KB, 256-aligned)
  // so one zero_i32 pass covers all three.
  int*   counts = (int*)alloc(N_NODES * 4);
  int*   cursor = (int*)alloc(N_NODES * 4);
  float* hm     = (float*)alloc(N_NODES * 4);
  int*   starts = (int*)alloc((N_NODES + 1) * 4);
  int*   adj    = (int*)alloc(NEDGE * 4);
  float* z      = (float*)alloc((HID_ / 2) * 4);

  // CSR build (ws is re-poisoned each call -> must zero). counts+cursor+hm
  // zeroed in ONE launch (12288 contiguous i32; 0x0 == 0.0f for hm).
  zero_i32<<<48, 256, 0, stream>>>(counts, 3 * N_NODES);
  hist_rows<<<NEDGE / 256, 256, 0, stream>>>(row, counts);
  scan4096<<<1, 1024, 0, stream>>>(counts, starts);
  fill_adj<<<NEDGE / 256, 256, 0, stream>>>(row, col, starts, cursor, adj);

  // fp8 conversions into fragment-major layout (one launch, slot dispatch)
  cvt_all<<<(int)(SL_W2 / 256), 256, 0, stream>>>(x, W_embed, W1, W2,
                                                  xf8, wef8, w1f8, w2f8);

  // embed: h0 = fp8(8 * (x @ We^T + be)), fragment-major out (gemm2's A)
  gemm_mx<<<256, 512, 0, stream>>>(xf8, wef8, h0f8, HID_, IN_DIM_,
                                   b_embed, G_STORE_MUL, 1);
  // layer 1: g = h0 @ W1^T (row-major out) ; h1 = fp8(...) fragment-major
  gemm_mx<<<256, 512, 0, stream>>>(h0f8, w1f8, g, HID_, HID_,
                                   nullptr, G_STORE_MUL, 0);
  aggr_f8out<<<N_NODES * 8, 64, 0, stream>>>(g, starts, adj, b1, h1f8);
  // layer 2: g = h1 @ W2^T (row-major out) ; hm[node] = mean relu (fused)
  gemm_mx<<<256, 512, 0, stream>>>(h1f8, w2f8, g, HID_, HID_,
                                   nullptr, G_STORE_MUL, 0);
  aggr_mean<<<N_NODES * 8, 64, 0, stream>>>(g, starts, adj, b2, hm);
  // classifier tail
  clf1<<<(HID_ / 2) / 4, 256, 0, stream>>>(Wc1, bc1, hm, z);
  clf2<<<1, 256, 0, stream>>>(Wc2, bc2, z, out);
}

// Round 10
// 431.065 us; speedup vs baseline: 1.0589x; 1.0589x over previous
//
#include <hip/hip_runtime.h>
#include <hip/hip_bf16.h>

// GNN: h = x@We^T + be; 2x { h = relu(segsum(h[col],row) @ W^T + b) };
// out = relu(mean(h,1) @ Wc1^T + bc1) @ Wc2^T + bc2   (scalar fp32)
//
// Restructure: relu((A h) W^T + b) == relu(A (h W^T) + b)  (A = sparse adj).
// R16: R14 structure (best, 70.3us) with ALL s_setprio REMOVED from the
// gemm loop. R15 LESSON: hand-interleaving reads/MFMA clusters regressed
// (79.7us) -- compiler scheduling wins (m141 analog). setprio hypothesis:
// T5 is documented to HURT lockstep barrier-synced GEMM (m190: -14TF) --
// prio-1 MFMA waves starve read-issuing waves -> global phase alternation
// (all-read burst / all-MFMA burst), matching R14's serial 5272 cyc/tile
// (= MFMA 2211 + LDS 2313 + writes 512). This round is the clean A/B.
// R14: GLOBAL fragment-major operands -- staging src base+(t&127)*16 (1KB
// contiguous/wave) AND lane-linear LDS reads (0 conflicts, HW-verified):
//   addr(row,k) = ((row>>4)*(K>>7) + (k>>7))*2048 + ((k>>4)&1)*1024
//               + ((((k>>5)&3)<<4) | (row&15))*16 + (k&15)
// Producers: cvt_all permuted; gemm1 epilogue permuted (permC=1);
// aggr_f8out permuted; g row-major (aggr gathers).
// R13 ERRATA: SQ_LDS_BANK_CONFLICT was 8/ds_read_b128 (real; 128B-stride
// rows). R12: XCD-slab aggr (2MB L2-resident). R11: aggr+mean fused.
// R10 LESSON: 12 live i32x8 frags spill -> keep the af reload schedule.
// GEMM schedule: 1 barrier/K-tile; boundary vmcnt(0) covered by a full
// tile of MFMA; compiler-counted lgkmcnt does fine sync.
//   - 256x256 tile, 512 threads, 8 waves (2Mx4N), BK=128, double-buffered
//     LDS (128 KiB), MX-scaled fp8 mfma_scale_f32_16x16x128_f8f6f4.
//   - XCD swizzle: 4x8 sub-rectangle of tiles per XCD (12 MB panel set).

#define N_NODES 4096
#define IN_DIM_ 512
#define HID_ 4096
#define NEDGE 65536

typedef float f32x4 __attribute__((ext_vector_type(4)));
typedef float f32x2 __attribute__((ext_vector_type(2)));
typedef unsigned short u16x8 __attribute__((ext_vector_type(8)));
typedef int i32x8 __attribute__((ext_vector_type(8)));

#define ACT_SCALE 8.0f     // activations fp8 = 8 x true
#define W_SCALE 256.0f     // weights fp8 = 256 x true
#define G_SCALE 8.0f       // g fp8 = 8 x true
// gemm acc = 2048 x true; fp8-store multiplier = 8/2048
#define G_STORE_MUL (8.0f / 2048.0f)

__device__ __forceinline__ unsigned short f2bf(float f) {
  unsigned u = __float_as_uint(f);
  return (unsigned short)((u + 0x7fffu + ((u >> 16) & 1u)) >> 16);  // RNE
}
__device__ __forceinline__ float bf2f(unsigned short h) {
  return __uint_as_float((unsigned)h << 16);
}
__device__ __forceinline__ unsigned char f2fp8(float f) {
  int w = __builtin_amdgcn_cvt_pk_fp8_f32(f, f, 0, false);  // OCP e4m3
  return (unsigned char)(w & 0xff);
}
// decode 4 fp8 bytes of w into acc[0..3] (+=)
__device__ __forceinline__ void fp8x4_acc(int w, float* acc) {
  f32x2 lo = __builtin_amdgcn_cvt_pk_f32_fp8(w, false);
  f32x2 hi = __builtin_amdgcn_cvt_pk_f32_fp8(w, true);
  acc[0] += lo[0]; acc[1] += lo[1]; acc[2] += hi[0]; acc[3] += hi[1];
}

// ---- fused fp32 -> fp8 e4m3 into FRAGMENT-MAJOR layout (R14) ----
// One thread = one 16B output slot S: decode S -> (row, k0..k0+15), read
// 64B of fp32, pack 16 fp8, write 16B at out+S*16 (contiguous writes).
// slot ranges (16B slots): x 131072 | We +131072 | W1 +1048576 | W2 +1048576
#define SL_X  131072L
#define SL_WE 262144L
#define SL_W1 1310720L
#define SL_W2 2359296L
__global__ __launch_bounds__(256) void cvt_all(
    const float* __restrict__ x, const float* __restrict__ We,
    const float* __restrict__ W1, const float* __restrict__ W2,
    unsigned char* __restrict__ xf8, unsigned char* __restrict__ wef8,
    unsigned char* __restrict__ w1f8, unsigned char* __restrict__ w2f8) {
  long S = (long)blockIdx.x * 256 + threadIdx.x;
  const float* src; unsigned char* dst; float sc; long So; int K, ktb;
  if (S < SL_X)       { src = x;  dst = xf8;  sc = ACT_SCALE; So = S;         K = 512;  ktb = 2; }
  else if (S < SL_WE) { src = We; dst = wef8; sc = W_SCALE;   So = S - SL_X;  K = 512;  ktb = 2; }
  else if (S < SL_W1) { src = W1; dst = w1f8; sc = W_SCALE;   So = S - SL_WE; K = 4096; ktb = 5; }
  else                { src = W2; dst = w2f8; sc = W_SCALE;   So = S - SL_W1; K = 4096; ktb = 5; }
  const long region = So >> 7;
  const int rem = (int)(So & 127);
  const int h = (rem >> 6) & 1, q = (rem >> 4) & 3, m = rem & 15;
  const long R16 = region >> ktb;
  const int kt = (int)(region & ((1 << ktb) - 1));
  const long row = R16 * 16 + m;
  const int k0 = kt * 128 + q * 32 + h * 16;
  const float* p = src + row * K + k0;
  const float4 a = *(const float4*)(p);
  const float4 b = *(const float4*)(p + 4);
  const float4 c = *(const float4*)(p + 8);
  const float4 d = *(const float4*)(p + 12);
  int w0 = __builtin_amdgcn_cvt_pk_fp8_f32(a.x * sc, a.y * sc, 0, false);
  w0 = __builtin_amdgcn_cvt_pk_fp8_f32(a.z * sc, a.w * sc, w0, true);
  int w1 = __builtin_amdgcn_cvt_pk_fp8_f32(b.x * sc, b.y * sc, 0, false);
  w1 = __builtin_amdgcn_cvt_pk_fp8_f32(b.z * sc, b.w * sc, w1, true);
  int w2 = __builtin_amdgcn_cvt_pk_fp8_f32(c.x * sc, c.y * sc, 0, false);
  w2 = __builtin_amdgcn_cvt_pk_fp8_f32(c.z * sc, c.w * sc, w2, true);
  int w3 = __builtin_amdgcn_cvt_pk_fp8_f32(d.x * sc, d.y * sc, 0, false);
  w3 = __builtin_amdgcn_cvt_pk_fp8_f32(d.z * sc, d.w * sc, w3, true);
  *(int4*)(dst + So * 16) = make_int4(w0, w1, w2, w3);
}

// ---------------- CSR build ----------------
__global__ __launch_bounds__(256) void zero_i32(int* __restrict__ p, int n) {
  int i = blockIdx.x * 256 + threadIdx.x;
  if (i < n) p[i] = 0;
}

__global__ __launch_bounds__(256) void hist_rows(const int* __restrict__ row,
                                                 int* __restrict__ counts) {
  int e = blockIdx.x * 256 + threadIdx.x;
  if (e < NEDGE) atomicAdd(&counts[row[e]], 1);
}

// exclusive scan of counts[4096] -> starts[4097]; single block of 1024 threads
__global__ __launch_bounds__(1024) void scan4096(const int* __restrict__ counts,
                                                 int* __restrict__ starts) {
  __shared__ int sa[1024], sb[1024];
  const int t = threadIdx.x;
  const int c0 = counts[t * 4], c1 = counts[t * 4 + 1],
            c2 = counts[t * 4 + 2], c3 = counts[t * 4 + 3];
  const int local = c0 + c1 + c2 + c3;
  sa[t] = local;
  __syncthreads();
  int* src = sa; int* dst = sb;
  for (int off = 1; off < 1024; off <<= 1) {
    int v = src[t];
    if (t >= off) v += src[t - off];
    dst[t] = v;
    __syncthreads();
    int* tmp = src; src = dst; dst = tmp;
  }
  const int excl = (t == 0) ? 0 : src[t - 1];
  starts[t * 4]     = excl;
  starts[t * 4 + 1] = excl + c0;
  starts[t * 4 + 2] = excl + c0 + c1;
  starts[t * 4 + 3] = excl + c0 + c1 + c2;
  if (t == 1023) starts[4096] = excl + local;
}

__global__ __launch_bounds__(256) void fill_adj(const int* __restrict__ row,
                                                const int* __restrict__ col,
                                                const int* __restrict__ starts,
                                                int* __restrict__ cursor,
                                                int* __restrict__ adj) {
  int e = blockIdx.x * 256 + threadIdx.x;
  if (e >= NEDGE) return;
  int r = row[e];
  int p = atomicAdd(&cursor[r], 1);
  adj[starts[r] + p] = col[e];
}

// ---- MX fp8 GEMM: C = fp8(mul*(A@B^T) [+ ACT_SCALE*bias]) ----
// A, B in fragment-major global layout; C row-major (permC=0) or
// fragment-major (permC=1). 256x256 tile, BK=128, 8 waves, 1 barrier/tile.
#define GLDS(gp, lp)                                                       \
  __builtin_amdgcn_global_load_lds(                                        \
      (const __attribute__((address_space(1))) void*)(gp),                 \
      (__attribute__((address_space(3))) void*)(lp), 16, 0, 0)

__global__ __launch_bounds__(512, 2) void gemm_mx(
    const unsigned char* __restrict__ A, const unsigned char* __restrict__ B,
    unsigned char* __restrict__ C, int N, int K,
    const float* __restrict__ bias, float mul, int permC) {
  __shared__ unsigned char lds[131072];   // [A dbuf 2x32K][B dbuf 2x32K]
  const int t = threadIdx.x;
  // XCD swizzle: XCD x owns a 4(bm) x 8(bn) sub-rectangle of the 16x16 tile
  // grid (bijective for nwg=256). 32 co-resident blocks/XCD share
  // 4 A-panels + 8 B-panels; per-K-step working set 384 KB << 4 MB L2.
  const int w = blockIdx.x;
  const int xcd = w & 7, j = w >> 3;
  const int bm = ((xcd & 3) * 4 + (j & 3)) * 256;
  const int bn = ((xcd >> 2) * 8 + (j >> 2)) * 256;
  const int wave = t >> 6, lane = t & 63;
  const int wm = (wave >> 2) * 128, wn = (wave & 3) * 64;
  const int m16 = lane & 15, quad = lane >> 4;

  f32x4 acc[8][4] = {};

  const int KT = K >> 7;
  // staging (fragment-major global): thread t, inst i, k-tile kt sources
  // base + ((bm>>4) + i*4 + (t>>7))*KT*2048 + kt*2048 + (t&127)*16 and
  // writes LDS byte i*8192 + t*16. Per wave: 1KB contiguous global reads.
  const unsigned char* Ag = A + ((size_t)(bm >> 4) + (t >> 7)) * KT * 2048 + (t & 127) * 16;
  const unsigned char* Bg = B + ((size_t)(bn >> 4) + (t >> 7)) * KT * 2048 + (t & 127) * 16;
  const size_t istep = (size_t)8192 * KT;      // +4 row-blocks per inst
  unsigned char* Als = lds;
  unsigned char* Bls = lds + 65536;
  const int sd = t * 16;
  const int lane16 = lane * 16;

#define STAGE_A(i, kb, dst) GLDS(Ag + (kb) + (size_t)(i) * istep, (dst) + (i) * 8192 + sd)
#define STAGE_B(i, kb, dst) GLDS(Bg + (kb) + (size_t)(i) * istep, (dst) + (i) * 8192 + sd)

  // lane-linear conflict-free fragment read (R13-verified: 0 conflicts)
#define LDFRAG(dst, base, fb)                                              \
  {                                                                        \
    const unsigned char* _p = (base) + (fb) * 2048 + lane16;               \
    const int4 _lo = *(const int4*)(_p);                                   \
    const int4 _hi = *(const int4*)(_p + 1024);                            \
    dst[0] = _lo.x; dst[1] = _lo.y; dst[2] = _lo.z; dst[3] = _lo.w;        \
    dst[4] = _hi.x; dst[5] = _hi.y; dst[6] = _hi.z; dst[7] = _hi.w;        \
  }

#define MFMA(r, c, afr, bfr)                                               \
  acc[r][c] = __builtin_amdgcn_mfma_scale_f32_16x16x128_f8f6f4(            \
      afr, bfr, acc[r][c], 0, 0, 0, 0x7f7f7f7f, 0, 0x7f7f7f7f)

  // A frag block base (16-row frags): wm/16; B frag base: wn/16
  const int afb = (wave >> 2) * 8;
  const int bfb = (wave & 3) * 4;

  // prologue: stage tile 0 into buf 0 (only exposed wait of the loop)
  STAGE_A(0, 0, Als); STAGE_A(1, 0, Als); STAGE_A(2, 0, Als); STAGE_A(3, 0, Als);
  STAGE_B(0, 0, Bls); STAGE_B(1, 0, Bls); STAGE_B(2, 0, Bls); STAGE_B(3, 0, Bls);
  asm volatile("s_waitcnt vmcnt(0)" ::: "memory");
  __builtin_amdgcn_s_barrier();

  i32x8 af[4], bf01[2], bf23[2];

  for (int tt = 0; tt < KT; ++tt) {
    unsigned char* Ab = Als + (tt & 1) * 32768;
    unsigned char* Bb = Bls + (tt & 1) * 32768;
    unsigned char* An = Als + ((tt + 1) & 1) * 32768;
    unsigned char* Bn = Bls + ((tt + 1) & 1) * 32768;
    const int kbn = (tt + 1) * 2048;
    const bool more = (tt + 1) < KT;

    // Issue all M0-3 + B fragment reads, then next-tile A staging; MFMA
    // clusters follow with compiler-counted lgkmcnt -- later clusters'
    // reads drain under earlier clusters' MFMAs. No intra-tile barriers,
    // NO setprio (R16: T5 hurts lockstep GEMM -- starves read-issuing
    // waves while MFMA waves run at prio 1 -> global phase alternation).
    LDFRAG(af[0], Ab, afb + 0);
    LDFRAG(af[1], Ab, afb + 1);
    LDFRAG(af[2], Ab, afb + 2);
    LDFRAG(af[3], Ab, afb + 3);
    LDFRAG(bf01[0], Bb, bfb + 0);
    LDFRAG(bf01[1], Bb, bfb + 1);
    LDFRAG(bf23[0], Bb, bfb + 2);
    LDFRAG(bf23[1], Bb, bfb + 3);
    if (more) {
      STAGE_A(0, kbn, An); STAGE_A(1, kbn, An);
      STAGE_A(2, kbn, An); STAGE_A(3, kbn, An);
    }
    MFMA(0, 0, af[0], bf01[0]); MFMA(0, 1, af[0], bf01[1]);
    MFMA(1, 0, af[1], bf01[0]); MFMA(1, 1, af[1], bf01[1]);
    MFMA(2, 0, af[2], bf01[0]); MFMA(2, 1, af[2], bf01[1]);
    MFMA(3, 0, af[3], bf01[0]); MFMA(3, 1, af[3], bf01[1]);
    if (more) {
      STAGE_B(0, kbn, Bn); STAGE_B(1, kbn, Bn);
      STAGE_B(2, kbn, Bn); STAGE_B(3, kbn, Bn);
    }
    MFMA(0, 2, af[0], bf23[0]); MFMA(0, 3, af[0], bf23[1]);
    MFMA(1, 2, af[1], bf23[0]); MFMA(1, 3, af[1], bf23[1]);
    MFMA(2, 2, af[2], bf23[0]); MFMA(2, 3, af[2], bf23[1]);
    MFMA(3, 2, af[3], bf23[0]); MFMA(3, 3, af[3], bf23[1]);
    // reload af with row frags 4-7 (WAR on af: HW scoreboard orders the
    // LDS writeback after the consuming MFMAs read their operands)
    LDFRAG(af[0], Ab, afb + 4);
    LDFRAG(af[1], Ab, afb + 5);
    LDFRAG(af[2], Ab, afb + 6);
    LDFRAG(af[3], Ab, afb + 7);
    MFMA(4, 0, af[0], bf01[0]); MFMA(4, 1, af[0], bf01[1]);
    MFMA(5, 0, af[1], bf01[0]); MFMA(5, 1, af[1], bf01[1]);
    MFMA(6, 0, af[2], bf01[0]); MFMA(6, 1, af[2], bf01[1]);
    MFMA(7, 0, af[3], bf01[0]); MFMA(7, 1, af[3], bf01[1]);
    MFMA(4, 2, af[0], bf23[0]); MFMA(4, 3, af[0], bf23[1]);
    MFMA(5, 2, af[1], bf23[0]); MFMA(5, 3, af[1], bf23[1]);
    MFMA(6, 2, af[2], bf23[0]); MFMA(6, 3, af[2], bf23[1]);
    MFMA(7, 2, af[3], bf23[0]); MFMA(7, 3, af[3], bf23[1]);
    if (more) {
      // tile-boundary: t+1's staging (issued ~a tile of MFMA ago) has
      // landed; all buf-cur reads were consumed above. ONLY barrier.
      asm volatile("s_waitcnt vmcnt(0)" ::: "memory");
      __builtin_amdgcn_sched_barrier(0);
      __builtin_amdgcn_s_barrier();
    }
  }

#undef MFMA
#undef LDFRAG
#undef STAGE_A
#undef STAGE_B

  // C/D layout (16x16 family, shape-determined): col=lane&15, row=quad*4+reg
  if (permC) {
    const int KTN = N >> 7;
#pragma unroll
    for (int r = 0; r < 8; ++r) {
#pragma unroll
      for (int c = 0; c < 4; ++c) {
        const int rb = ((bm + wm) >> 4) + r;          // row-block (rows>>4)
        const int colb = bn + wn + c * 16;            // 16-aligned col base
        const float bv = bias ? ACT_SCALE * bias[colb + m16] : 0.0f;
        const size_t base = ((size_t)rb * KTN + (colb >> 7)) * 2048
                          + (((colb >> 4) & 1) << 10)
                          + (((colb >> 5) & 3) << 8) + m16;
#pragma unroll
        for (int i = 0; i < 4; ++i) {
          C[base + (quad * 4 + i) * 16] = f2fp8(acc[r][c][i] * mul + bv);
        }
      }
    }
  } else {
#pragma unroll
    for (int r = 0; r < 8; ++r) {
#pragma unroll
      for (int c = 0; c < 4; ++c) {
        const int row0 = bm + wm + r * 16 + quad * 4;
        const int col = bn + wn + c * 16 + m16;
        const float bv = bias ? ACT_SCALE * bias[col] : 0.0f;
#pragma unroll
        for (int i = 0; i < 4; ++i) {
          C[(size_t)(row0 + i) * N + col] = f2fp8(acc[r][c][i] * mul + bv);
        }
      }
    }
  }
}
#undef GLDS

// ---- aggregation (fp8 g in, row-major): h = relu(sum g/G + b) -> fp8,
// written FRAGMENT-MAJOR (h1f8 is the next gemm's A operand).
// One wave per (node, 512-col slab); xcd = b&7 = slab -> 2 MB L2-resident.
__global__ __launch_bounds__(64) void aggr_f8out(
    const unsigned char* __restrict__ g, const int* __restrict__ starts,
    const int* __restrict__ adj, const float* __restrict__ bias,
    unsigned char* __restrict__ hout) {
  const int node = blockIdx.x >> 3;
  const int f0 = (blockIdx.x & 7) * 512 + threadIdx.x * 8;
  float acc[8] = {0, 0, 0, 0, 0, 0, 0, 0};
  const int s = starts[node], e = starts[node + 1];
  int j = s;
  for (; j + 4 <= e; j += 4) {
    const int c0 = adj[j], c1 = adj[j + 1], c2 = adj[j + 2], c3 = adj[j + 3];
    int2 v0 = *(const int2*)(g + (size_t)c0 * HID_ + f0);
    int2 v1 = *(const int2*)(g + (size_t)c1 * HID_ + f0);
    int2 v2 = *(const int2*)(g + (size_t)c2 * HID_ + f0);
    int2 v3 = *(const int2*)(g + (size_t)c3 * HID_ + f0);
    fp8x4_acc(v0.x, acc);     fp8x4_acc(v0.y, acc + 4);
    fp8x4_acc(v1.x, acc);     fp8x4_acc(v1.y, acc + 4);
    fp8x4_acc(v2.x, acc);     fp8x4_acc(v2.y, acc + 4);
    fp8x4_acc(v3.x, acc);     fp8x4_acc(v3.y, acc + 4);
  }
  for (; j < e; ++j) {
    int2 v = *(const int2*)(g + (size_t)adj[j] * HID_ + f0);
    fp8x4_acc(v.x, acc);      fp8x4_acc(v.y, acc + 4);
  }
  const float4 b0 = *(const float4*)(bias + f0);
  const float4 b1 = *(const float4*)(bias + f0 + 4);
  const float bb[8] = {b0.x, b0.y, b0.z, b0.w, b1.x, b1.y, b1.z, b1.w};
  float v[8];
#pragma unroll
  for (int i = 0; i < 8; ++i)
    v[i] = ACT_SCALE * fmaxf(acc[i] * (1.0f / G_SCALE) + bb[i], 0.0f);
  int w0 = __builtin_amdgcn_cvt_pk_fp8_f32(v[0], v[1], 0, false);
  w0 = __builtin_amdgcn_cvt_pk_fp8_f32(v[2], v[3], w0, true);
  int w1 = __builtin_amdgcn_cvt_pk_fp8_f32(v[4], v[5], 0, false);
  w1 = __builtin_amdgcn_cvt_pk_fp8_f32(v[6], v[7], w1, true);
  // fragment-major dest (K = HID, KT = 32); f0&15 in {0,8} -> 8B in-slot
  const size_t oaddr = ((size_t)(node >> 4) * 32 + (f0 >> 7)) * 2048
                     + (((f0 >> 4) & 1) << 10)
                     + (((f0 >> 5) & 3) << 8) + ((node & 15) << 4) + (f0 & 15);
  *(int2*)(hout + oaddr) = make_int2(w0, w1);
}

// ---- fused final aggregation + row mean: hm[node] += sum_f relu(.)/HID ----
// (h2 never materialized; g row-major; same XCD-slab structure)
__global__ __launch_bounds__(64) void aggr_mean(
    const unsigned char* __restrict__ g, const int* __restrict__ starts,
    const int* __restrict__ adj, const float* __restrict__ bias,
    float* __restrict__ hm) {
  const int node = blockIdx.x >> 3;
  const int f0 = (blockIdx.x & 7) * 512 + threadIdx.x * 8;
  float acc[8] = {0, 0, 0, 0, 0, 0, 0, 0};
  const int s = starts[node], e = starts[node + 1];
  int j = s;
  for (; j + 4 <= e; j += 4) {
    const int c0 = adj[j], c1 = adj[j + 1], c2 = adj[j + 2], c3 = adj[j + 3];
    int2 v0 = *(const int2*)(g + (size_t)c0 * HID_ + f0);
    int2 v1 = *(const int2*)(g + (size_t)c1 * HID_ + f0);
    int2 v2 = *(const int2*)(g + (size_t)c2 * HID_ + f0);
    int2 v3 = *(const int2*)(g + (size_t)c3 * HID_ + f0);
    fp8x4_acc(v0.x, acc);     fp8x4_acc(v0.y, acc + 4);
    fp8x4_acc(v1.x, acc);     fp8x4_acc(v1.y, acc + 4);
    fp8x4_acc(v2.x, acc);     fp8x4_acc(v2.y, acc + 4);
    fp8x4_acc(v3.x, acc);     fp8x4_acc(v3.y, acc + 4);
  }
  for (; j < e; ++j) {
    int2 v = *(const int2*)(g + (size_t)adj[j] * HID_ + f0);
    fp8x4_acc(v.x, acc);      fp8x4_acc(v.y, acc + 4);
  }
  const float4 b0 = *(const float4*)(bias + f0);
  const float4 b1 = *(const float4*)(bias + f0 + 4);
  const float bb[8] = {b0.x, b0.y, b0.z, b0.w, b1.x, b1.y, b1.z, b1.w};
  float local = 0.f;
#pragma unroll
  for (int i = 0; i < 8; ++i)
    local += fmaxf(acc[i] * (1.0f / G_SCALE) + bb[i], 0.0f);
  for (int off = 32; off > 0; off >>= 1) local += __shfl_down(local, off);
  if (threadIdx.x == 0)
    atomicAdd(&hm[node], local * (1.0f / (float)HID_));
}

// ---------------- z[j] = relu(Wc1[j,:].hm + bc1[j]), one wave per j ----------------
__global__ __launch_bounds__(256) void clf1(const float* __restrict__ Wc1,
                                            const float* __restrict__ bc1,
                                            const float* __restrict__ hm,
                                            float* __restrict__ z) {
  const int wave = threadIdx.x >> 6, lane = threadIdx.x & 63;
  const int j = blockIdx.x * 4 + wave;
  const float* w = Wc1 + (size_t)j * HID_;
  float s = 0.f;
  for (int i = lane; i < HID_; i += 64) s += w[i] * hm[i];
  for (int off = 32; off > 0; off >>= 1) s += __shfl_down(s, off);
  if (lane == 0) z[j] = fmaxf(s + bc1[j], 0.0f);
}

// ---------------- out = Wc2.z + bc2 ----------------
__global__ __launch_bounds__(256) void clf2(const float* __restrict__ Wc2,
                                            const float* __restrict__ bc2,
                                            const float* __restrict__ z,
                                            float* __restrict__ out) {
  const int t = threadIdx.x;
  float s = 0.f;
  for (int i = t; i < HID_ / 2; i += 256) s += z[i] * Wc2[i];
  for (int off = 32; off > 0; off >>= 1) s += __shfl_down(s, off);
  __shared__ float ws[4];
  if ((t & 63) == 0) ws[t >> 6] = s;
  __syncthreads();
  if (t == 0) out[0] = ws[0] + ws[1] + ws[2] + ws[3] + bc2[0];
}

extern "C" void kernel_launch(void* const* d_in, const int* in_sizes, int n_in,
                              void* d_out, int out_size, void* d_ws, size_t ws_size,
                              hipStream_t stream) {
  (void)in_sizes; (void)n_in; (void)out_size; (void)ws_size;
  const float* x       = (const float*)d_in[0];
  const int*   edge    = (const int*)d_in[1];
  const int*   row     = edge;
  const int*   col     = edge + NEDGE;
  const float* W_embed = (const float*)d_in[2];
  const float* b_embed = (const float*)d_in[3];
  const float* W1      = (const float*)d_in[4];
  const float* b1      = (const float*)d_in[5];
  const float* W2      = (const float*)d_in[6];
  const float* b2      = (const float*)d_in[7];
  const float* Wc1     = (const float*)d_in[8];
  const float* bc1     = (const float*)d_in[9];
  const float* Wc2     = (const float*)d_in[10];
  const float* bc2     = (const float*)d_in[11];
  float* out = (float*)d_out;

  char* ws = (char*)d_ws;
  size_t off = 0;
  auto alloc = [&](size_t bytes) {
    char* p = ws + off;
    off += (bytes + 255) & ~(size_t)255;
    return p;
  };
  unsigned char*  xf8  = (unsigned char*)alloc((size_t)N_NODES * IN_DIM_);
  unsigned char*  wef8 = (unsigned char*)alloc((size_t)HID_ * IN_DIM_);
  unsigned char*  w1f8 = (unsigned char*)alloc((size_t)HID_ * HID_);
  unsigned char*  w2f8 = (unsigned char*)alloc((size_t)HID_ * HID_);
  unsigned char*  h0f8 = (unsigned char*)alloc((size_t)N_NODES * HID_);
  unsigned char*  h1f8 = (unsigned char*)alloc((size_t)N_NODES * HID_);
  unsigned char*  g    = (unsigned char*)alloc((size_t)N_NODES * HID_);
  // counts | cursor | hm are allocated adjacently (each 16 KB, 256-aligned)
  // so one zero_i32 pass covers all three.
  int*   counts = (int*)alloc(N_NODES * 4);
  int*   cursor = (int*)alloc(N_NODES * 4);
  float* hm     = (float*)alloc(N_NODES * 4);
  int*   starts = (int*)alloc((N_NODES + 1) * 4);
  int*   adj    = (int*)alloc(NEDGE * 4);
  float* z      = (float*)alloc((HID_ / 2) * 4);

  // CSR build (ws is re-poisoned each call -> must zero). counts+cursor+hm
  // zeroed in ONE launch (12288 contiguous i32; 0x0 == 0.0f for hm).
  zero_i32<<<48, 256, 0, stream>>>(counts, 3 * N_NODES);
  hist_rows<<<NEDGE / 256, 256, 0, stream>>>(row, counts);
  scan4096<<<1, 1024, 0, stream>>>(counts, starts);
  fill_adj<<<NEDGE / 256, 256, 0, stream>>>(row, col, starts, cursor, adj);

  // fp8 conversions into fragment-major layout (one launch, slot dispatch)
  cvt_all<<<(int)(SL_W2 / 256), 256, 0, stream>>>(x, W_embed, W1, W2,
                                                  xf8, wef8, w1f8, w2f8);

  // embed: h0 = fp8(8 * (x @ We^T + be)), fragment-major out (gemm2's A)
  gemm_mx<<<256, 512, 0, stream>>>(xf8, wef8, h0f8, HID_, IN_DIM_,
                                   b_embed, G_STORE_MUL, 1);
  // layer 1: g = h0 @ W1^T (row-major out) ; h1 = fp8(...) fragment-major
  gemm_mx<<<256, 512, 0, stream>>>(h0f8, w1f8, g, HID_, HID_,
                                   nullptr, G_STORE_MUL, 0);
  aggr_f8out<<<N_NODES * 8, 64, 0, stream>>>(g, starts, adj, b1, h1f8);
  // layer 2: g = h1 @ W2^T (row-major out) ; hm[node] = mean relu (fused)
  gemm_mx<<<256, 512, 0, stream>>>(h1f8, w2f8, g, HID_, HID_,
                                   nullptr, G_STORE_MUL, 0);
  aggr_mean<<<N_NODES * 8, 64, 0, stream>>>(g, starts, adj, b2, hm);
  // classifier tail
  clf1<<<(HID_ / 2) / 4, 256, 0, stream>>>(Wc1, bc1, hm, z);
  clf2<<<1, 256, 0, stream>>>(Wc2, bc2, z, out);
}